// Round 23
// baseline (189.260 us; speedup 1.0000x reference)
//
#include <hip/hip_runtime.h>

// Problem constants (from reference)
#define N_NODES 100000
#define N_EDGES 1600000
#define N_REL   5
#define NCOARSE  391                         // ceil(N_NODES / 256) coarse buckets
#define CAP      8192                        // pe capacity per coarse bucket (avg ~4092)

using bf16x8 = __attribute__((ext_vector_type(8))) short;
using f32x4  = __attribute__((ext_vector_type(4))) float;
using f32x2  = __attribute__((ext_vector_type(2))) float;

__device__ __forceinline__ unsigned short f2bf(float f) {
    unsigned int u = __float_as_uint(f);
    u += 0x7fffu + ((u >> 16) & 1u);          // RNE
    return (unsigned short)(u >> 16);
}
__device__ __forceinline__ float bfu(unsigned short u) { return __uint_as_float((unsigned int)u << 16); }
__device__ __forceinline__ float bflo(unsigned int p) { return __uint_as_float(p << 16); }
__device__ __forceinline__ float bfhi(unsigned int p) { return __uint_as_float(p & 0xffff0000u); }

// ---------------------------------------------------------------------------
// Pass 1: append edges into coarse (dst>>8) regions of pe.
// Record = (src | rel<<17 | dlow8<<20, ew).  512-entry LDS histogram.
// ---------------------------------------------------------------------------
__global__ __launch_bounds__(1024) void partition_append(
    const int* __restrict__ src, const int* __restrict__ dstv,
    const float* __restrict__ ew, const int* __restrict__ et,
    int* __restrict__ ccur, int2* __restrict__ pe) {
    __shared__ int lh[512];
    __shared__ int lb[512];
    int tid = threadIdx.x;
    if (tid < 512) lh[tid] = 0;
    __syncthreads();
    int base = blockIdx.x * 4096;
    int key[4], rank[4], meta[4];
    float w[4];
    #pragma unroll
    for (int i = 0; i < 4; ++i) {
        int e = base + i * 1024 + tid;
        key[i] = -1;
        if (e < N_EDGES) {
            int d = dstv[e];
            key[i] = d >> 8;
            meta[i] = src[e] | (et[e] << 17) | ((d & 255) << 20);
            w[i] = ew[e];
            rank[i] = atomicAdd(&lh[key[i]], 1);
        }
    }
    __syncthreads();
    if (tid < 512) {
        int c = lh[tid];
        lb[tid] = (c && tid < NCOARSE) ? atomicAdd(&ccur[tid], c) : 0;
    }
    __syncthreads();
    #pragma unroll
    for (int i = 0; i < 4; ++i)
        if (key[i] >= 0) {
            int pos = lb[key[i]] + rank[i];
            if (pos < CAP)
                pe[((size_t)key[i] << 13) + pos] = make_int2(meta[i], __float_as_int(w[i]));
        }
}

// Pass 2 (tiny): exclusive scan of NCOARSE coarse counts -> global bases.
__global__ __launch_bounds__(512) void cscan(const int* __restrict__ ccur,
                                             int* __restrict__ cstart) {
    __shared__ int lds[512];
    int tid = threadIdx.x;
    int v = (tid < NCOARSE) ? ccur[tid] : 0;
    lds[tid] = v;
    __syncthreads();
    for (int d = 1; d < 512; d <<= 1) {
        int t = (tid >= d) ? lds[tid - d] : 0;
        __syncthreads();
        lds[tid] += t;
        __syncthreads();
    }
    if (tid < NCOARSE) cstart[tid] = lds[tid] - v;
}

// ---------------------------------------------------------------------------
// Pass 3: one block per coarse bucket (391 blocks). Fine histogram (<=1280),
// wave-shfl scan, per-node descriptors, dense scatter (relation-sorted
// within node). 1/deg folded into w; rel kept in bits 17-19.
// ---------------------------------------------------------------------------
__global__ __launch_bounds__(1024) void bucket_sort(
    const int* __restrict__ ccnt, const int* __restrict__ cstart,
    const int2* __restrict__ pe, int2* __restrict__ edges,
    int* __restrict__ nbase, int2* __restrict__ nbp) {
    int cb = blockIdx.x;
    int node0 = cb << 8;
    if (node0 >= N_NODES) return;
    int nNodes = N_NODES - node0; if (nNodes > 256) nNodes = 256;
    int nf = nNodes * N_REL;                 // <= 1280
    __shared__ int hist[1280];
    __shared__ int cur[1280];
    __shared__ int wtot[16];
    __shared__ int woff[16];
    int tid = threadIdx.x;
    int wid = tid >> 6, lane = tid & 63;
    int cnt = ccnt[cb]; if (cnt > CAP) cnt = CAP;
    int gbase = cstart[cb];
    const int2* my = pe + ((size_t)cb << 13);

    for (int i = tid; i < nf; i += 1024) hist[i] = 0;
    __syncthreads();
    for (int i = tid; i < cnt; i += 1024) {
        int m = my[i].x;
        atomicAdd(&hist[((m >> 20) & 255) * N_REL + ((m >> 17) & 7)], 1);
    }
    __syncthreads();

    // exclusive scan over hist[0..nf): 2 elems/thread, wave shfl + 16 partials
    int t0 = tid * 2;
    int a0 = (t0 + 0 < nf) ? hist[t0 + 0] : 0;
    int a1 = (t0 + 1 < nf) ? hist[t0 + 1] : 0;
    int s = a0 + a1;
    int incl = s;
    #pragma unroll
    for (int d = 1; d < 64; d <<= 1) {
        int t = __shfl_up(incl, d);
        if (lane >= d) incl += t;
    }
    if (lane == 63) wtot[wid] = incl;
    __syncthreads();
    if (wid == 0 && lane < 16) {
        int v = wtot[lane];
        int inc2 = v;
        #pragma unroll
        for (int d = 1; d < 16; d <<= 1) {
            int t = __shfl_up(inc2, d);
            if (lane >= d) inc2 += t;
        }
        woff[lane] = inc2 - v;
    }
    __syncthreads();
    int excl = incl - s + woff[wid];
    if (t0 + 0 < nf) cur[t0 + 0] = excl;
    excl += a0;
    if (t0 + 1 < nf) cur[t0 + 1] = excl;
    __syncthreads();

    for (int i = tid; i < nNodes; i += 1024) {
        int b = i * N_REL;
        int c0 = cur[b];
        int deg = cur[b + 4] + hist[b + 4] - c0;
        nbase[node0 + i] = gbase + c0;
        nbp[node0 + i] = make_int2(0, deg);
    }
    __syncthreads();

    for (int i = tid; i < cnt; i += 1024) {
        int2 r = my[i];
        int fb = ((r.x >> 20) & 255) * N_REL + ((r.x >> 17) & 7);
        int pos = gbase + atomicAdd(&cur[fb], 1);
        float wf = __int_as_float(r.y) / (float)hist[fb];   // fold 1/deg
        edges[pos] = make_int2(r.x & 0xFFFFF, __float_as_int(wf)); // src|rel<<17
    }
}

// ---------------------------------------------------------------------------
// Feature conversion: x -> xh (bf16)
// ---------------------------------------------------------------------------
__global__ void cvt_feat(const float* __restrict__ x, ushort* __restrict__ xh) {
    int i = blockIdx.x * blockDim.x + threadIdx.x;   // float4 index
    if (i >= (N_NODES * 128) / 4) return;
    float4 v = reinterpret_cast<const float4*>(x)[i];
    ushort4 o;
    o.x = f2bf(v.x); o.y = f2bf(v.y); o.z = f2bf(v.z); o.w = f2bf(v.w);
    reinterpret_cast<ushort4*>(xh)[i] = o;
}

// ---------------------------------------------------------------------------
// Weight staging (one kernel). PERMUTED rows: within each seg, logical output
// col o sits at MFMA-B row j = (o&7)*16 + (o>>3), so MFMA lane p=(o>>3) owns
// 8 CONSECUTIVE outputs 8p..8p+7 -> packed 8B/16B epilogue stores in gemmZ.
// ---------------------------------------------------------------------------
__global__ void cvt_weights(const float* __restrict__ W1, const float* __restrict__ root1,
                            const float* __restrict__ W2, const float* __restrict__ root2,
                            ushort* __restrict__ Wt1b, ushort* __restrict__ Wt2s) {
    int i = blockIdx.x * blockDim.x + threadIdx.x;
    if (i < 768 * 128) {
        int o640 = i >> 7, k = i & 127;
        int seg = o640 >> 7, o = o640 & 127;
        float v;
        if (seg < 5) v = W1[((size_t)seg * 128 + k) * 128 + o];
        else         v = root1[k * 128 + o];
        int j = ((o & 7) << 4) | (o >> 3);          // permuted row within seg
        Wt1b[((size_t)(seg * 128 + j)) * 128 + k] = f2bf(v);
    } else if (i < 768 * 128 + 96 * 128) {
        int ii = i - 768 * 128;
        int o = ii >> 7, k = ii & 127;
        float v = (o < 16) ? root2[k * 16 + o]
                           : W2[((size_t)((o >> 4) - 1) * 128 + k) * 16 + (o & 15)];
        Wt2s[ii] = f2bf(v);
    }
}

// ---------------------------------------------------------------------------
// gemmZ: 64-row tiles (As 16 KB) + Bs 32 KB = 48 KB LDS -> 3 blocks/CU.
// grid = (1563 row-blocks, 2 seg-groups of 3). Permuted weight rows ->
// packed 8B (fp8) / 16B (bf16) epilogue stores.
// ---------------------------------------------------------------------------
__global__ __launch_bounds__(256) void gemmZ(
    const ushort* __restrict__ xh, const ushort* __restrict__ Wt1b,
    unsigned char* __restrict__ Zq, ushort* __restrict__ Zroot) {
    __shared__ ushort As[64 * 128];    // 16 KB
    __shared__ ushort Bs[128 * 128];   // 32 KB
    const int tid = threadIdx.x, lane = tid & 63, wave = tid >> 6;
    const int m0 = blockIdx.x * 64;
    const int seg0 = blockIdx.y * 3;

    #pragma unroll
    for (int u = 0; u < 4; ++u) {
        int idx = tid + u * 256;
        int row = idx >> 4, slot = idx & 15;
        int gr = m0 + row; if (gr >= N_NODES) gr = N_NODES - 1;
        float4 v = *reinterpret_cast<const float4*>(xh + (size_t)gr * 128 + slot * 8);
        int byte = row * 256 + ((slot ^ (row & 15)) << 4);
        *reinterpret_cast<float4*>(reinterpret_cast<char*>(As) + byte) = v;
    }

    for (int si = 0; si < 3; ++si) {
        int seg = seg0 + si;
        #pragma unroll
        for (int u = 0; u < 8; ++u) {
            int idx = tid + u * 256;
            int row = idx >> 4, slot = idx & 15;
            float4 v = *reinterpret_cast<const float4*>(
                Wt1b + ((size_t)(seg * 128 + row)) * 128 + slot * 8);
            int byte = row * 256 + ((slot ^ (row & 15)) << 4);
            *reinterpret_cast<float4*>(reinterpret_cast<char*>(Bs) + byte) = v;
        }
        __syncthreads();

        f32x4 acc[8] = {};
        #pragma unroll
        for (int ks = 0; ks < 4; ++ks) {
            bf16x8 af, bfr[8];
            {
                int row = wave * 16 + (lane & 15);
                int slot = ks * 4 + (lane >> 4);
                int byte = row * 256 + ((slot ^ (row & 15)) << 4);
                af = *reinterpret_cast<const bf16x8*>(
                    reinterpret_cast<const char*>(As) + byte);
            }
            #pragma unroll
            for (int nn = 0; nn < 8; ++nn) {
                int row = nn * 16 + (lane & 15);
                int slot = ks * 4 + (lane >> 4);
                int byte = row * 256 + ((slot ^ (row & 15)) << 4);
                bfr[nn] = *reinterpret_cast<const bf16x8*>(
                    reinterpret_cast<const char*>(Bs) + byte);
            }
            #pragma unroll
            for (int nn = 0; nn < 8; ++nn)
                acc[nn] = __builtin_amdgcn_mfma_f32_16x16x32_bf16(
                    af, bfr[nn], acc[nn], 0, 0, 0);
        }

        // packed epilogue: lane p owns cols 8p..8p+7 (acc[nn][q], nn = col&7)
        int p = lane & 15;
        int rloc = m0 + wave * 16 + (lane >> 4) * 4;
        if (seg < 5) {
            #pragma unroll
            for (int q = 0; q < 4; ++q) {
                int row = rloc + q;
                if (row < N_NODES) {
                    int d0 = __builtin_amdgcn_cvt_pk_fp8_f32(acc[0][q], acc[1][q], 0, false);
                    d0 = __builtin_amdgcn_cvt_pk_fp8_f32(acc[2][q], acc[3][q], d0, true);
                    int d1 = __builtin_amdgcn_cvt_pk_fp8_f32(acc[4][q], acc[5][q], 0, false);
                    d1 = __builtin_amdgcn_cvt_pk_fp8_f32(acc[6][q], acc[7][q], d1, true);
                    *reinterpret_cast<int2*>(Zq + (size_t)row * 640 + seg * 128 + p * 8) =
                        make_int2(d0, d1);
                }
            }
        } else {
            #pragma unroll
            for (int q = 0; q < 4; ++q) {
                int row = rloc + q;
                if (row < N_NODES) {
                    uint4 v;
                    v.x = (unsigned)f2bf(acc[0][q]) | ((unsigned)f2bf(acc[1][q]) << 16);
                    v.y = (unsigned)f2bf(acc[2][q]) | ((unsigned)f2bf(acc[3][q]) << 16);
                    v.z = (unsigned)f2bf(acc[4][q]) | ((unsigned)f2bf(acc[5][q]) << 16);
                    v.w = (unsigned)f2bf(acc[6][q]) | ((unsigned)f2bf(acc[7][q]) << 16);
                    *reinterpret_cast<uint4*>(Zroot + (size_t)row * 128 + p * 8) = v;
                }
            }
        }
        __syncthreads();   // Bs reads done before next restage
    }
}

// ---------------------------------------------------------------------------
// gather2Y: output-space aggregation + h epilogue (LDS only) + fused Yh GEMM.
// 1024-thread block = 16 waves = 16 nodes. Each wave gathers its node (same
// inner loop as before), writes h-row to swizzled LDS; barrier; waves 0-5
// each compute one 16-col fragment of Yh[16][96] = h_lds @ Wt2^T (B-frags
// direct from L2-resident Wt2s). h never touches HBM; gemmYh eliminated.
// ---------------------------------------------------------------------------
__global__ __launch_bounds__(1024) void gather2Y(
    const ushort* __restrict__ Zq,     // fp8 [N][640] viewed as ushort
    const int2* __restrict__ edges,    // (src|rel<<17, w/deg) sorted per node
    const int* __restrict__ nbase, const int2* __restrict__ nbp,
    const ushort* __restrict__ Zroot,  // bf16 [N][128]
    const float* __restrict__ b1,      // f32 [128]
    const ushort* __restrict__ Wt2,    // bf16 [96][128] (L2-resident)
    ushort* __restrict__ Yh) {         // bf16 [N][96]
    __shared__ ushort hs[16 * 128];    // 4 KB, swizzled rows
    int wid = threadIdx.x >> 6, lane = threadIdx.x & 63;
    int n = __builtin_amdgcn_readfirstlane(blockIdx.x * 16 + wid);
    int o0  = __builtin_amdgcn_readfirstlane(nbase[n]);
    int deg = __builtin_amdgcn_readfirstlane(nbp[n].y);
    f32x2 acc = {0.f, 0.f};

    if (deg <= 64) {
        int2 er = (lane < deg) ? edges[o0 + lane] : make_int2(0, 0);
        int deg8 = (deg + 7) & ~7;
        for (int j = 0; j < deg8; j += 8) {
            unsigned short q[8];
            float w[8];
            #pragma unroll
            for (int u = 0; u < 8; ++u) {
                int m = __builtin_amdgcn_readlane(er.x, j + u);
                int s5 = (m & 0x1FFFF) * 5 + ((m >> 17) & 7);
                q[u] = Zq[((size_t)s5 << 6) + lane];
            }
            #pragma unroll
            for (int u = 0; u < 8; ++u)
                w[u] = __uint_as_float(__builtin_amdgcn_readlane(er.y, j + u));
            #pragma unroll
            for (int u = 0; u < 8; ++u) {
                f32x2 f = __builtin_amdgcn_cvt_pk_f32_fp8((int)q[u], false);
                f32x2 ws = {w[u], w[u]};
                acc = __builtin_elementwise_fma(ws, f, acc);
            }
        }
    } else {
        for (int base = o0; base < o0 + deg; base += 64) {
            int rem = o0 + deg - base;
            int mcap = rem > 64 ? 64 : rem;
            int2 er = (lane < mcap) ? edges[base + lane] : make_int2(0, 0);
            int m8 = (mcap + 7) & ~7;
            for (int j = 0; j < m8; j += 8) {
                unsigned short q[8];
                float w[8];
                #pragma unroll
                for (int u = 0; u < 8; ++u) {
                    int m = __builtin_amdgcn_readlane(er.x, j + u);
                    int s5 = (m & 0x1FFFF) * 5 + ((m >> 17) & 7);
                    q[u] = Zq[((size_t)s5 << 6) + lane];
                }
                #pragma unroll
                for (int u = 0; u < 8; ++u)
                    w[u] = __uint_as_float(__builtin_amdgcn_readlane(er.y, j + u));
                #pragma unroll
                for (int u = 0; u < 8; ++u) {
                    f32x2 f = __builtin_amdgcn_cvt_pk_f32_fp8((int)q[u], false);
                    f32x2 ws = {w[u], w[u]};
                    acc = __builtin_elementwise_fma(ws, f, acc);
                }
            }
        }
    }

    // h = relu(Zroot + agg + b1) -> LDS (swizzled rows, 4 B per lane)
    unsigned int zr = reinterpret_cast<const unsigned int*>(Zroot)[(size_t)n * 64 + lane];
    float h0 = fmaxf(bflo(zr) + acc.x + b1[2 * lane], 0.f);
    float h1 = fmaxf(bfhi(zr) + acc.y + b1[2 * lane + 1], 0.f);
    unsigned int packed = (unsigned int)f2bf(h0) | ((unsigned int)f2bf(h1) << 16);
    {
        int s16 = lane >> 2;                       // 16B slot within row
        int byte = wid * 256 + ((s16 ^ (wid & 15)) << 4) + ((lane * 4) & 15);
        *reinterpret_cast<unsigned int*>(reinterpret_cast<char*>(hs) + byte) = packed;
    }
    __syncthreads();

    // Yh[16][96] = h_lds @ Wt2^T: waves 0-5 each do one 16-col fragment
    if (wid < 6) {
        f32x4 a2 = {};
        #pragma unroll
        for (int ks = 0; ks < 4; ++ks) {
            bf16x8 af, bfr;
            {
                int row = lane & 15;
                int slot = ks * 4 + (lane >> 4);
                int byte = row * 256 + ((slot ^ (row & 15)) << 4);
                af = *reinterpret_cast<const bf16x8*>(
                    reinterpret_cast<const char*>(hs) + byte);
            }
            {
                int brow = wid * 16 + (lane & 15);
                bfr = *reinterpret_cast<const bf16x8*>(
                    Wt2 + (size_t)brow * 128 + (ks * 4 + (lane >> 4)) * 8);
            }
            a2 = __builtin_amdgcn_mfma_f32_16x16x32_bf16(af, bfr, a2, 0, 0, 0);
        }
        int c = wid * 16 + (lane & 15);
        #pragma unroll
        for (int q = 0; q < 4; ++q) {
            int row = (lane >> 4) * 4 + q;
            int gn = blockIdx.x * 16 + row;
            Yh[(size_t)gn * 96 + c] = f2bf(a2[q]);
        }
    }
}

// ---------------------------------------------------------------------------
// Layer-2 aggregate + bias + log_softmax, fused. 4 nodes/wave, 16 lanes/node
// (16-record batch + shfl walk = 16 independent Yh gathers in flight).
// ---------------------------------------------------------------------------
__global__ __launch_bounds__(256) void agg2_softmax(
    const ushort* __restrict__ Yh, const int2* __restrict__ edges,
    const int* __restrict__ nbase, const int2* __restrict__ nbp,
    const float* __restrict__ b2, float* __restrict__ out) {
    int wave = threadIdx.x >> 6, lane = threadIdx.x & 63;
    int q = lane >> 4, c = lane & 15;
    int n = (blockIdx.x * 4 + wave) * 4 + q;
    int nn = (n < N_NODES) ? n : N_NODES - 1;
    int o0 = nbase[nn];
    int deg = nbp[nn].y;

    float val = bfu(Yh[(size_t)nn * 96 + c]) + b2[c];

    for (int b = 0; b < deg; b += 16) {
        int2 er = (b + c < deg) ? edges[o0 + b + c] : make_int2(0, 0);
        #pragma unroll
        for (int j = 0; j < 16; ++j) {
            int m = __shfl(er.x, q * 16 + j);
            float w = __uint_as_float(__shfl(er.y, q * 16 + j));
            int s = m & 0x1FFFF;
            int rel = (m >> 17) & 7;
            val = fmaf(w, bfu(Yh[(size_t)s * 96 + 16 + rel * 16 + c]), val);
        }
    }

    // log_softmax over the 16-lane group
    float mx = val;
    #pragma unroll
    for (int i = 1; i < 16; i <<= 1) mx = fmaxf(mx, __shfl_xor(mx, i));
    float ex = expf(val - mx);
    float ssum = ex;
    #pragma unroll
    for (int i = 1; i < 16; i <<= 1) ssum += __shfl_xor(ssum, i);
    float r = val - mx - logf(ssum);
    if (n < N_NODES) out[(size_t)n * 16 + c] = r;
}

// ---------------------------------------------------------------------------
extern "C" void kernel_launch(void* const* d_in, const int* in_sizes, int n_in,
                              void* d_out, int out_size, void* d_ws, size_t ws_size,
                              hipStream_t stream) {
    const float* x     = (const float*)d_in[0];
    const int*   ei    = (const int*)d_in[1];
    const int*   src   = ei;
    const int*   dst   = ei + N_EDGES;
    const float* ew    = (const float*)d_in[2];
    const int*   et    = (const int*)d_in[3];
    const float* W1    = (const float*)d_in[4];
    const float* root1 = (const float*)d_in[5];
    const float* b1    = (const float*)d_in[6];
    const float* W2    = (const float*)d_in[7];
    const float* root2 = (const float*)d_in[8];
    const float* b2    = (const float*)d_in[9];
    float* out = (float*)d_out;

    // workspace layout (~175 MB, all disjoint)
    char* ws = (char*)d_ws;
    int*    ccur    = (int*)ws;                        //      2,048 B
    int*    cstart  = (int*)(ws + 2048);               //      2,048 B
    int*    nbase   = (int*)(ws + 4096);               //    400,000 B
    int2*   nbp     = (int2*)(ws + 404096);            //    800,000 B
    int2*   edges   = (int2*)(ws + 1204096);           // 12,800,000 B
    ushort* xh      = (ushort*)(ws + 14004096);        // 25,600,000 B
    ushort* Wt1b    = (ushort*)(ws + 39604096);        //    196,608 B (768x128)
    ushort* Wt2s    = (ushort*)(ws + 39800704);        //     24,576 B
    ushort* Zroot   = (ushort*)(ws + 39825280);        // 25,600,000 B
    unsigned char* Zq = (unsigned char*)(ws + 65425280); // 64,000,000 B
    ushort* Yh      = (ushort*)(ws + 129425280);       // 19,200,000 B
    int2*   pe      = (int2*)(ws + 148625280);         // 25,624,576 B (391*8192*8)

    // --- conversions ---
    cvt_feat<<<((N_NODES * 128 / 4) + 255) / 256, 256, 0, stream>>>(x, xh);
    cvt_weights<<<((768 * 128 + 96 * 128) + 255) / 256, 256, 0, stream>>>(
        W1, root1, W2, root2, Wt1b, Wt2s);

    // --- build (dst,rel)-bucketed CSR: 3 passes (391 coarse buckets) ---
    hipMemsetAsync(ccur, 0, 2048, stream);
    partition_append<<<(N_EDGES + 4095) / 4096, 1024, 0, stream>>>(src, dst, ew, et, ccur, pe);
    cscan<<<1, 512, 0, stream>>>(ccur, cstart);
    bucket_sort<<<NCOARSE, 1024, 0, stream>>>(ccur, cstart, pe, edges, nbase, nbp);

    // --- layer 1, transform-first: Zq = fp8(xh @ W1stack^T), Zroot = bf16(xh @ root1^T) ---
    gemmZ<<<dim3((N_NODES + 63) / 64, 2), 256, 0, stream>>>(xh, Wt1b, Zq, Zroot);

    // --- aggregation + h (LDS) + fused Yh GEMM (h never hits HBM) ---
    gather2Y<<<N_NODES / 16, 1024, 0, stream>>>(
        (const ushort*)Zq, edges, nbase, nbp, Zroot, b1, Wt2s, Yh);

    // --- layer-2 aggregate + bias + log_softmax ---
    agg2_softmax<<<(N_NODES + 15) / 16, 256, 0, stream>>>(
        Yh, edges, nbase, nbp, b2, out);
}

// Round 24
// 181.421 us; speedup vs baseline: 1.0432x; 1.0432x over previous
//
#include <hip/hip_runtime.h>

// Problem constants (from reference)
#define N_NODES 100000
#define N_EDGES 1600000
#define N_REL   5
#define NCOARSE  391                         // ceil(N_NODES / 256) coarse buckets
#define CAP      8192                        // pe capacity per coarse bucket (avg ~4092)

using bf16x8 = __attribute__((ext_vector_type(8))) short;
using f32x4  = __attribute__((ext_vector_type(4))) float;
using f32x2  = __attribute__((ext_vector_type(2))) float;

__device__ __forceinline__ unsigned short f2bf(float f) {
    unsigned int u = __float_as_uint(f);
    u += 0x7fffu + ((u >> 16) & 1u);          // RNE
    return (unsigned short)(u >> 16);
}
__device__ __forceinline__ float bfu(unsigned short u) { return __uint_as_float((unsigned int)u << 16); }
__device__ __forceinline__ float bflo(unsigned int p) { return __uint_as_float(p << 16); }
__device__ __forceinline__ float bfhi(unsigned int p) { return __uint_as_float(p & 0xffff0000u); }

// ---------------------------------------------------------------------------
// Pass 1: append edges into coarse (dst>>8) regions of pe.
// Record = (src | rel<<17 | dlow8<<20, ew).  512-entry LDS histogram.
// ---------------------------------------------------------------------------
__global__ __launch_bounds__(1024) void partition_append(
    const int* __restrict__ src, const int* __restrict__ dstv,
    const float* __restrict__ ew, const int* __restrict__ et,
    int* __restrict__ ccur, int2* __restrict__ pe) {
    __shared__ int lh[512];
    __shared__ int lb[512];
    int tid = threadIdx.x;
    if (tid < 512) lh[tid] = 0;
    __syncthreads();
    int base = blockIdx.x * 4096;
    int key[4], rank[4], meta[4];
    float w[4];
    #pragma unroll
    for (int i = 0; i < 4; ++i) {
        int e = base + i * 1024 + tid;
        key[i] = -1;
        if (e < N_EDGES) {
            int d = dstv[e];
            key[i] = d >> 8;
            meta[i] = src[e] | (et[e] << 17) | ((d & 255) << 20);
            w[i] = ew[e];
            rank[i] = atomicAdd(&lh[key[i]], 1);
        }
    }
    __syncthreads();
    if (tid < 512) {
        int c = lh[tid];
        lb[tid] = (c && tid < NCOARSE) ? atomicAdd(&ccur[tid], c) : 0;
    }
    __syncthreads();
    #pragma unroll
    for (int i = 0; i < 4; ++i)
        if (key[i] >= 0) {
            int pos = lb[key[i]] + rank[i];
            if (pos < CAP)
                pe[((size_t)key[i] << 13) + pos] = make_int2(meta[i], __float_as_int(w[i]));
        }
}

// Pass 2 (tiny): exclusive scan of NCOARSE coarse counts -> global bases.
__global__ __launch_bounds__(512) void cscan(const int* __restrict__ ccur,
                                             int* __restrict__ cstart) {
    __shared__ int lds[512];
    int tid = threadIdx.x;
    int v = (tid < NCOARSE) ? ccur[tid] : 0;
    lds[tid] = v;
    __syncthreads();
    for (int d = 1; d < 512; d <<= 1) {
        int t = (tid >= d) ? lds[tid - d] : 0;
        __syncthreads();
        lds[tid] += t;
        __syncthreads();
    }
    if (tid < NCOARSE) cstart[tid] = lds[tid] - v;
}

// ---------------------------------------------------------------------------
// Pass 3: one block per coarse bucket (391 blocks). Fine histogram (<=1280),
// wave-shfl scan, per-node descriptors, dense scatter (relation-sorted
// within node). 1/deg folded into w; rel kept in bits 17-19.
// ---------------------------------------------------------------------------
__global__ __launch_bounds__(1024) void bucket_sort(
    const int* __restrict__ ccnt, const int* __restrict__ cstart,
    const int2* __restrict__ pe, int2* __restrict__ edges,
    int* __restrict__ nbase, int2* __restrict__ nbp) {
    int cb = blockIdx.x;
    int node0 = cb << 8;
    if (node0 >= N_NODES) return;
    int nNodes = N_NODES - node0; if (nNodes > 256) nNodes = 256;
    int nf = nNodes * N_REL;                 // <= 1280
    __shared__ int hist[1280];
    __shared__ int cur[1280];
    __shared__ int wtot[16];
    __shared__ int woff[16];
    int tid = threadIdx.x;
    int wid = tid >> 6, lane = tid & 63;
    int cnt = ccnt[cb]; if (cnt > CAP) cnt = CAP;
    int gbase = cstart[cb];
    const int2* my = pe + ((size_t)cb << 13);

    for (int i = tid; i < nf; i += 1024) hist[i] = 0;
    __syncthreads();
    for (int i = tid; i < cnt; i += 1024) {
        int m = my[i].x;
        atomicAdd(&hist[((m >> 20) & 255) * N_REL + ((m >> 17) & 7)], 1);
    }
    __syncthreads();

    // exclusive scan over hist[0..nf): 2 elems/thread, wave shfl + 16 partials
    int t0 = tid * 2;
    int a0 = (t0 + 0 < nf) ? hist[t0 + 0] : 0;
    int a1 = (t0 + 1 < nf) ? hist[t0 + 1] : 0;
    int s = a0 + a1;
    int incl = s;
    #pragma unroll
    for (int d = 1; d < 64; d <<= 1) {
        int t = __shfl_up(incl, d);
        if (lane >= d) incl += t;
    }
    if (lane == 63) wtot[wid] = incl;
    __syncthreads();
    if (wid == 0 && lane < 16) {
        int v = wtot[lane];
        int inc2 = v;
        #pragma unroll
        for (int d = 1; d < 16; d <<= 1) {
            int t = __shfl_up(inc2, d);
            if (lane >= d) inc2 += t;
        }
        woff[lane] = inc2 - v;
    }
    __syncthreads();
    int excl = incl - s + woff[wid];
    if (t0 + 0 < nf) cur[t0 + 0] = excl;
    excl += a0;
    if (t0 + 1 < nf) cur[t0 + 1] = excl;
    __syncthreads();

    for (int i = tid; i < nNodes; i += 1024) {
        int b = i * N_REL;
        int c0 = cur[b];
        int deg = cur[b + 4] + hist[b + 4] - c0;
        nbase[node0 + i] = gbase + c0;
        nbp[node0 + i] = make_int2(0, deg);
    }
    __syncthreads();

    for (int i = tid; i < cnt; i += 1024) {
        int2 r = my[i];
        int fb = ((r.x >> 20) & 255) * N_REL + ((r.x >> 17) & 7);
        int pos = gbase + atomicAdd(&cur[fb], 1);
        float wf = __int_as_float(r.y) / (float)hist[fb];   // fold 1/deg
        edges[pos] = make_int2(r.x & 0xFFFFF, __float_as_int(wf)); // src|rel<<17
    }
}

// ---------------------------------------------------------------------------
// Feature conversion: x -> xh (bf16)
// ---------------------------------------------------------------------------
__global__ void cvt_feat(const float* __restrict__ x, ushort* __restrict__ xh) {
    int i = blockIdx.x * blockDim.x + threadIdx.x;   // float4 index
    if (i >= (N_NODES * 128) / 4) return;
    float4 v = reinterpret_cast<const float4*>(x)[i];
    ushort4 o;
    o.x = f2bf(v.x); o.y = f2bf(v.y); o.z = f2bf(v.z); o.w = f2bf(v.w);
    reinterpret_cast<ushort4*>(xh)[i] = o;
}

// ---------------------------------------------------------------------------
// Weight staging (one kernel). PERMUTED rows: within each seg, logical output
// col o sits at MFMA-B row j = (o&7)*16 + (o>>3), so MFMA lane p=(o>>3) owns
// 8 CONSECUTIVE outputs 8p..8p+7 -> packed 8B/16B epilogue stores in gemmZ.
// ---------------------------------------------------------------------------
__global__ void cvt_weights(const float* __restrict__ W1, const float* __restrict__ root1,
                            const float* __restrict__ W2, const float* __restrict__ root2,
                            ushort* __restrict__ Wt1b, ushort* __restrict__ Wt2s) {
    int i = blockIdx.x * blockDim.x + threadIdx.x;
    if (i < 768 * 128) {
        int o640 = i >> 7, k = i & 127;
        int seg = o640 >> 7, o = o640 & 127;
        float v;
        if (seg < 5) v = W1[((size_t)seg * 128 + k) * 128 + o];
        else         v = root1[k * 128 + o];
        int j = ((o & 7) << 4) | (o >> 3);          // permuted row within seg
        Wt1b[((size_t)(seg * 128 + j)) * 128 + k] = f2bf(v);
    } else if (i < 768 * 128 + 96 * 128) {
        int ii = i - 768 * 128;
        int o = ii >> 7, k = ii & 127;
        float v = (o < 16) ? root2[k * 16 + o]
                           : W2[((size_t)((o >> 4) - 1) * 128 + k) * 16 + (o & 15)];
        Wt2s[ii] = f2bf(v);
    }
}

// ---------------------------------------------------------------------------
// gemmZ: 64-row tiles (As 16 KB) + Bs 32 KB = 48 KB LDS -> 3 blocks/CU.
// grid = (1563 row-blocks, 2 seg-groups of 3). Permuted weight rows ->
// packed 8B (fp8) / 16B (bf16) epilogue stores.
// ---------------------------------------------------------------------------
__global__ __launch_bounds__(256) void gemmZ(
    const ushort* __restrict__ xh, const ushort* __restrict__ Wt1b,
    unsigned char* __restrict__ Zq, ushort* __restrict__ Zroot) {
    __shared__ ushort As[64 * 128];    // 16 KB
    __shared__ ushort Bs[128 * 128];   // 32 KB
    const int tid = threadIdx.x, lane = tid & 63, wave = tid >> 6;
    const int m0 = blockIdx.x * 64;
    const int seg0 = blockIdx.y * 3;

    #pragma unroll
    for (int u = 0; u < 4; ++u) {
        int idx = tid + u * 256;
        int row = idx >> 4, slot = idx & 15;
        int gr = m0 + row; if (gr >= N_NODES) gr = N_NODES - 1;
        float4 v = *reinterpret_cast<const float4*>(xh + (size_t)gr * 128 + slot * 8);
        int byte = row * 256 + ((slot ^ (row & 15)) << 4);
        *reinterpret_cast<float4*>(reinterpret_cast<char*>(As) + byte) = v;
    }

    for (int si = 0; si < 3; ++si) {
        int seg = seg0 + si;
        #pragma unroll
        for (int u = 0; u < 8; ++u) {
            int idx = tid + u * 256;
            int row = idx >> 4, slot = idx & 15;
            float4 v = *reinterpret_cast<const float4*>(
                Wt1b + ((size_t)(seg * 128 + row)) * 128 + slot * 8);
            int byte = row * 256 + ((slot ^ (row & 15)) << 4);
            *reinterpret_cast<float4*>(reinterpret_cast<char*>(Bs) + byte) = v;
        }
        __syncthreads();

        f32x4 acc[8] = {};
        #pragma unroll
        for (int ks = 0; ks < 4; ++ks) {
            bf16x8 af, bfr[8];
            {
                int row = wave * 16 + (lane & 15);
                int slot = ks * 4 + (lane >> 4);
                int byte = row * 256 + ((slot ^ (row & 15)) << 4);
                af = *reinterpret_cast<const bf16x8*>(
                    reinterpret_cast<const char*>(As) + byte);
            }
            #pragma unroll
            for (int nn = 0; nn < 8; ++nn) {
                int row = nn * 16 + (lane & 15);
                int slot = ks * 4 + (lane >> 4);
                int byte = row * 256 + ((slot ^ (row & 15)) << 4);
                bfr[nn] = *reinterpret_cast<const bf16x8*>(
                    reinterpret_cast<const char*>(Bs) + byte);
            }
            #pragma unroll
            for (int nn = 0; nn < 8; ++nn)
                acc[nn] = __builtin_amdgcn_mfma_f32_16x16x32_bf16(
                    af, bfr[nn], acc[nn], 0, 0, 0);
        }

        // packed epilogue: lane p owns cols 8p..8p+7 (acc[nn][q], nn = col&7)
        int p = lane & 15;
        int rloc = m0 + wave * 16 + (lane >> 4) * 4;
        if (seg < 5) {
            #pragma unroll
            for (int q = 0; q < 4; ++q) {
                int row = rloc + q;
                if (row < N_NODES) {
                    int d0 = __builtin_amdgcn_cvt_pk_fp8_f32(acc[0][q], acc[1][q], 0, false);
                    d0 = __builtin_amdgcn_cvt_pk_fp8_f32(acc[2][q], acc[3][q], d0, true);
                    int d1 = __builtin_amdgcn_cvt_pk_fp8_f32(acc[4][q], acc[5][q], 0, false);
                    d1 = __builtin_amdgcn_cvt_pk_fp8_f32(acc[6][q], acc[7][q], d1, true);
                    *reinterpret_cast<int2*>(Zq + (size_t)row * 640 + seg * 128 + p * 8) =
                        make_int2(d0, d1);
                }
            }
        } else {
            #pragma unroll
            for (int q = 0; q < 4; ++q) {
                int row = rloc + q;
                if (row < N_NODES) {
                    uint4 v;
                    v.x = (unsigned)f2bf(acc[0][q]) | ((unsigned)f2bf(acc[1][q]) << 16);
                    v.y = (unsigned)f2bf(acc[2][q]) | ((unsigned)f2bf(acc[3][q]) << 16);
                    v.z = (unsigned)f2bf(acc[4][q]) | ((unsigned)f2bf(acc[5][q]) << 16);
                    v.w = (unsigned)f2bf(acc[6][q]) | ((unsigned)f2bf(acc[7][q]) << 16);
                    *reinterpret_cast<uint4*>(Zroot + (size_t)row * 128 + p * 8) = v;
                }
            }
        }
        __syncthreads();   // Bs reads done before next restage
    }
}

// ---------------------------------------------------------------------------
// gather2: output-space aggregation + fused h epilogue.
// One wave per node; per edge read 128 B of Zq at (src*5+rel)*128 (fp8).
// f32x2 accumulator (lowers to v_pk_fma_f32). Tail: h = relu(Zroot+agg+b1).
// ---------------------------------------------------------------------------
__global__ __launch_bounds__(256) void gather2(
    const ushort* __restrict__ Zq,     // fp8 [N][640] viewed as ushort
    const int2* __restrict__ edges,    // (src|rel<<17, w/deg) sorted per node
    const int* __restrict__ nbase, const int2* __restrict__ nbp,
    const ushort* __restrict__ Zroot,  // bf16 [N][128]
    const float* __restrict__ b1,      // f32 [128]
    ushort* __restrict__ h) {          // bf16 [N][128]
    int n = __builtin_amdgcn_readfirstlane(blockIdx.x * 4 + (threadIdx.x >> 6));
    int lane = threadIdx.x & 63;
    int o0  = __builtin_amdgcn_readfirstlane(nbase[n]);
    int deg = __builtin_amdgcn_readfirstlane(nbp[n].y);
    f32x2 acc = {0.f, 0.f};

    if (deg <= 64) {
        int2 er = (lane < deg) ? edges[o0 + lane] : make_int2(0, 0);
        int deg8 = (deg + 7) & ~7;
        for (int j = 0; j < deg8; j += 8) {
            unsigned short q[8];
            float w[8];
            #pragma unroll
            for (int u = 0; u < 8; ++u) {
                int m = __builtin_amdgcn_readlane(er.x, j + u);
                int s5 = (m & 0x1FFFF) * 5 + ((m >> 17) & 7);
                q[u] = Zq[((size_t)s5 << 6) + lane];
            }
            #pragma unroll
            for (int u = 0; u < 8; ++u)
                w[u] = __uint_as_float(__builtin_amdgcn_readlane(er.y, j + u));
            #pragma unroll
            for (int u = 0; u < 8; ++u) {
                f32x2 f = __builtin_amdgcn_cvt_pk_f32_fp8((int)q[u], false);
                f32x2 ws = {w[u], w[u]};
                acc = __builtin_elementwise_fma(ws, f, acc);
            }
        }
    } else {
        for (int base = o0; base < o0 + deg; base += 64) {
            int rem = o0 + deg - base;
            int mcap = rem > 64 ? 64 : rem;
            int2 er = (lane < mcap) ? edges[base + lane] : make_int2(0, 0);
            int m8 = (mcap + 7) & ~7;
            for (int j = 0; j < m8; j += 8) {
                unsigned short q[8];
                float w[8];
                #pragma unroll
                for (int u = 0; u < 8; ++u) {
                    int m = __builtin_amdgcn_readlane(er.x, j + u);
                    int s5 = (m & 0x1FFFF) * 5 + ((m >> 17) & 7);
                    q[u] = Zq[((size_t)s5 << 6) + lane];
                }
                #pragma unroll
                for (int u = 0; u < 8; ++u)
                    w[u] = __uint_as_float(__builtin_amdgcn_readlane(er.y, j + u));
                #pragma unroll
                for (int u = 0; u < 8; ++u) {
                    f32x2 f = __builtin_amdgcn_cvt_pk_f32_fp8((int)q[u], false);
                    f32x2 ws = {w[u], w[u]};
                    acc = __builtin_elementwise_fma(ws, f, acc);
                }
            }
        }
    }

    // fused epilogue: h = relu(Zroot + agg + b1)
    unsigned int zr = reinterpret_cast<const unsigned int*>(Zroot)[(size_t)n * 64 + lane];
    float h0 = fmaxf(bflo(zr) + acc.x + b1[2 * lane], 0.f);
    float h1 = fmaxf(bfhi(zr) + acc.y + b1[2 * lane + 1], 0.f);
    reinterpret_cast<unsigned int*>(h)[(size_t)n * 64 + lane] =
        (unsigned int)f2bf(h0) | ((unsigned int)f2bf(h1) << 16);
}

// ---------------------------------------------------------------------------
// gemmYh: Yh[n][96] = h[n][128] @ Wt2s[96][128]^T  (Bs staged in LDS)
// ---------------------------------------------------------------------------
__global__ __launch_bounds__(256) void gemmYh(
    const ushort* __restrict__ h, const ushort* __restrict__ Wt2,
    ushort* __restrict__ Yh) {
    __shared__ ushort As[128 * 128];   // 32 KB
    __shared__ ushort Bs[96 * 128];    // 24 KB
    const int tid = threadIdx.x, lane = tid & 63, wave = tid >> 6;
    const int m0 = blockIdx.x * 128;

    #pragma unroll
    for (int u = 0; u < 8; ++u) {
        int idx = tid + u * 256;
        int row = idx >> 4, slot = idx & 15;
        int gr = m0 + row; if (gr >= N_NODES) gr = N_NODES - 1;
        float4 v = *reinterpret_cast<const float4*>(h + (size_t)gr * 128 + slot * 8);
        int byte = row * 256 + ((slot ^ (row & 15)) << 4);
        *reinterpret_cast<float4*>(reinterpret_cast<char*>(As) + byte) = v;
    }
    #pragma unroll
    for (int u = 0; u < 6; ++u) {
        int idx = tid + u * 256;
        int row = idx >> 4, slot = idx & 15;
        float4 v = *reinterpret_cast<const float4*>(Wt2 + (size_t)row * 128 + slot * 8);
        int byte = row * 256 + ((slot ^ (row & 15)) << 4);
        *reinterpret_cast<float4*>(reinterpret_cast<char*>(Bs) + byte) = v;
    }
    __syncthreads();

    f32x4 acc2[2][6] = {};
    #pragma unroll
    for (int ks = 0; ks < 4; ++ks) {
        bf16x8 af[2], bfr[6];
        #pragma unroll
        for (int m = 0; m < 2; ++m) {
            int row = wave * 32 + m * 16 + (lane & 15);
            int slot = ks * 4 + (lane >> 4);
            int byte = row * 256 + ((slot ^ (row & 15)) << 4);
            af[m] = *reinterpret_cast<const bf16x8*>(
                reinterpret_cast<const char*>(As) + byte);
        }
        #pragma unroll
        for (int nn = 0; nn < 6; ++nn) {
            int row = nn * 16 + (lane & 15);
            int slot = ks * 4 + (lane >> 4);
            int byte = row * 256 + ((slot ^ (row & 15)) << 4);
            bfr[nn] = *reinterpret_cast<const bf16x8*>(
                reinterpret_cast<const char*>(Bs) + byte);
        }
        #pragma unroll
        for (int m = 0; m < 2; ++m)
            #pragma unroll
            for (int nn = 0; nn < 6; ++nn)
                acc2[m][nn] = __builtin_amdgcn_mfma_f32_16x16x32_bf16(
                    af[m], bfr[nn], acc2[m][nn], 0, 0, 0);
    }

    #pragma unroll
    for (int m = 0; m < 2; ++m) {
        int rloc = m0 + wave * 32 + m * 16 + (lane >> 4) * 4;
        #pragma unroll
        for (int nn = 0; nn < 6; ++nn) {
            int c = nn * 16 + (lane & 15);
            #pragma unroll
            for (int q = 0; q < 4; ++q) {
                int row = rloc + q;
                if (row < N_NODES) Yh[(size_t)row * 96 + c] = f2bf(acc2[m][nn][q]);
            }
        }
    }
}

// ---------------------------------------------------------------------------
// Layer-2 aggregate + bias + log_softmax, fused. 4 nodes/wave, 16 lanes/node
// (16-record batch + shfl walk = 16 independent Yh gathers in flight).
// ---------------------------------------------------------------------------
__global__ __launch_bounds__(256) void agg2_softmax(
    const ushort* __restrict__ Yh, const int2* __restrict__ edges,
    const int* __restrict__ nbase, const int2* __restrict__ nbp,
    const float* __restrict__ b2, float* __restrict__ out) {
    int wave = threadIdx.x >> 6, lane = threadIdx.x & 63;
    int q = lane >> 4, c = lane & 15;
    int n = (blockIdx.x * 4 + wave) * 4 + q;
    int nn = (n < N_NODES) ? n : N_NODES - 1;
    int o0 = nbase[nn];
    int deg = nbp[nn].y;

    float val = bfu(Yh[(size_t)nn * 96 + c]) + b2[c];

    for (int b = 0; b < deg; b += 16) {
        int2 er = (b + c < deg) ? edges[o0 + b + c] : make_int2(0, 0);
        #pragma unroll
        for (int j = 0; j < 16; ++j) {
            int m = __shfl(er.x, q * 16 + j);
            float w = __uint_as_float(__shfl(er.y, q * 16 + j));
            int s = m & 0x1FFFF;
            int rel = (m >> 17) & 7;
            val = fmaf(w, bfu(Yh[(size_t)s * 96 + 16 + rel * 16 + c]), val);
        }
    }

    // log_softmax over the 16-lane group
    float mx = val;
    #pragma unroll
    for (int i = 1; i < 16; i <<= 1) mx = fmaxf(mx, __shfl_xor(mx, i));
    float ex = expf(val - mx);
    float ssum = ex;
    #pragma unroll
    for (int i = 1; i < 16; i <<= 1) ssum += __shfl_xor(ssum, i);
    float r = val - mx - logf(ssum);
    if (n < N_NODES) out[(size_t)n * 16 + c] = r;
}

// ---------------------------------------------------------------------------
extern "C" void kernel_launch(void* const* d_in, const int* in_sizes, int n_in,
                              void* d_out, int out_size, void* d_ws, size_t ws_size,
                              hipStream_t stream) {
    const float* x     = (const float*)d_in[0];
    const int*   ei    = (const int*)d_in[1];
    const int*   src   = ei;
    const int*   dst   = ei + N_EDGES;
    const float* ew    = (const float*)d_in[2];
    const int*   et    = (const int*)d_in[3];
    const float* W1    = (const float*)d_in[4];
    const float* root1 = (const float*)d_in[5];
    const float* b1    = (const float*)d_in[6];
    const float* W2    = (const float*)d_in[7];
    const float* root2 = (const float*)d_in[8];
    const float* b2    = (const float*)d_in[9];
    float* out = (float*)d_out;

    // workspace layout (~200 MB, all disjoint)
    char* ws = (char*)d_ws;
    int*    ccur    = (int*)ws;                        //      2,048 B
    int*    cstart  = (int*)(ws + 2048);               //      2,048 B
    int*    nbase   = (int*)(ws + 4096);               //    400,000 B
    int2*   nbp     = (int2*)(ws + 404096);            //    800,000 B
    int2*   edges   = (int2*)(ws + 1204096);           // 12,800,000 B
    ushort* xh      = (ushort*)(ws + 14004096);        // 25,600,000 B
    ushort* Wt1b    = (ushort*)(ws + 39604096);        //    196,608 B (768x128)
    ushort* Wt2s    = (ushort*)(ws + 39800704);        //     24,576 B
    ushort* Zroot   = (ushort*)(ws + 39825280);        // 25,600,000 B
    ushort* h       = (ushort*)(ws + 65425280);        // 25,600,000 B
    unsigned char* Zq = (unsigned char*)(ws + 91025280); // 64,000,000 B
    ushort* Yh      = (ushort*)(ws + 155025280);       // 19,200,000 B
    int2*   pe      = (int2*)(ws + 174225280);         // 25,624,576 B (391*8192*8)

    // --- conversions ---
    cvt_feat<<<((N_NODES * 128 / 4) + 255) / 256, 256, 0, stream>>>(x, xh);
    cvt_weights<<<((768 * 128 + 96 * 128) + 255) / 256, 256, 0, stream>>>(
        W1, root1, W2, root2, Wt1b, Wt2s);

    // --- build (dst,rel)-bucketed CSR: 3 passes (391 coarse buckets) ---
    hipMemsetAsync(ccur, 0, 2048, stream);
    partition_append<<<(N_EDGES + 4095) / 4096, 1024, 0, stream>>>(src, dst, ew, et, ccur, pe);
    cscan<<<1, 512, 0, stream>>>(ccur, cstart);
    bucket_sort<<<NCOARSE, 1024, 0, stream>>>(ccur, cstart, pe, edges, nbase, nbp);

    // --- layer 1, transform-first: Zq = fp8(xh @ W1stack^T), Zroot = bf16(xh @ root1^T) ---
    gemmZ<<<dim3((N_NODES + 63) / 64, 2), 256, 0, stream>>>(xh, Wt1b, Zq, Zroot);

    // --- output-space aggregation + fused h = relu(Zroot + agg + b1) ---
    gather2<<<N_NODES / 4, 256, 0, stream>>>(
        (const ushort*)Zq, edges, nbase, nbp, Zroot, b1, h);

    // --- Yh = h @ Wt2s^T ---
    gemmYh<<<(N_NODES + 127) / 128, 256, 0, stream>>>(h, Wt2s, Yh);

    // --- layer-2 aggregate + bias + log_softmax ---
    agg2_softmax<<<(N_NODES + 15) / 16, 256, 0, stream>>>(
        Yh, edges, nbase, nbp, b2, out);
}